// Round 1
// baseline (388.807 us; speedup 1.0000x reference)
//
#include <hip/hip_runtime.h>

// GCN layer on MI355X — round 10: XCD-sliced gather.
//   M1:  memsetAsync(bhist+gcurz, 0, 2KB)
//   K1 prep_hist:      Wsw swizzle + BN consts (blocks 0-63) FUSED with
//                      bucket histogram (all 391 blocks)
//   K2 scatter_linear: bucket_scatter (391 blocks) FUSED with linear_mfma
//                      (1563 blocks). Linear now stores h in GROUP-MAJOR
//                      layout: h[g][node][16 cols] bf16, g = col/16, so each
//                      16-col slice is a contiguous 3.2MB region.
//   K3 bucket_to_csr:  per-bucket LDS csr segment -> off + csr (coalesced)
//   K4 gather_bn_relu: NEW — block's column group g = blockIdx&7 pins the
//                      group to one XCD (round-robin dispatch heuristic);
//                      group slice (3.2MB) fits the 4MB per-XCD L2, turning
//                      the random h[src] gather into L2 hits. Wave = 1 dst x
//                      16 cols, lanes = (8 edges x 8 uints), shfl_xor reduce.
//                      csr/off re-read x8 (+48MB fetch) traded for ~95MB of
//                      eliminated random re-fetch (FETCH 179MB -> ~85MB).
// Fusion forces ebuf != h  -> NEED 45.6MB; tier-2 (ws >= 32.8MB, proven) runs
// the same kernels un-fused with ebuf aliasing h; atomic fallback last.
// mean(h[src]) = mean(x[src])@W + b (linearity); deg=0 -> sum=0 -> relu(sh).

#define NN 100000
#define NE 1600000
#define CC 128
#define BN_EPS 1e-5f
#define LBLK 1563     // ceil(NN/64) linear blocks
#define LSTR 136      // LDS row stride in bf16 (128 + 8 pad)
#define NBUK 256      // dst buckets
#define DPB 391       // dsts per bucket (256*391 = 100096 >= NN)
#define ACH 4096      // edges per scatter block
#define ABLK 391      // ceil(NE/ACH)
#define CAP 10240     // to_csr LDS segment capacity (mean 6250, huge margin)

typedef __attribute__((ext_vector_type(8))) short bf16x8;
typedef __attribute__((ext_vector_type(4))) float f32x4;

static __device__ __forceinline__ short f2bf(float f) {
  union { float f; unsigned u; } v; v.f = f;
  unsigned r = (v.u + 0x7FFF + ((v.u >> 16) & 1)) >> 16;  // RNE
  return (short)r;
}
static __device__ __forceinline__ float bflo(unsigned p) {
  return __uint_as_float(p << 16);
}
static __device__ __forceinline__ float bfhi(unsigned p) {
  return __uint_as_float(p & 0xffff0000u);
}

// 256-wide Hillis-Steele scan in LDS; leaves a[] exclusive, returns excl[t].
static __device__ __forceinline__ int excl_scan256(int* a, int t, int v) {
  a[t] = v;
  __syncthreads();
  for (int d = 1; d < 256; d <<= 1) {
    const int x = (t >= d) ? a[t - d] : 0;
    __syncthreads();
    a[t] += x;
    __syncthreads();
  }
  const int incl = a[t];
  __syncthreads();
  a[t] = incl - v;
  __syncthreads();
  return incl - v;
}

// ---------------------------------------------------------------------------
// K1: prep (Wsw swizzle, col-permuted so D-lane m holds natural cols m*8..+7;
// BN scale/shift + bias) on blocks 0-63, bucket histogram on all 391 blocks.
// bhist pre-zeroed by the M1 memset.
// ---------------------------------------------------------------------------
__global__ __launch_bounds__(256) void prep_hist(
    const float* __restrict__ W, const float* __restrict__ bias,
    const float* __restrict__ gamma, const float* __restrict__ beta,
    const float* __restrict__ rmean, const float* __restrict__ rvar,
    const int* __restrict__ ei, short* __restrict__ Wsw,
    float* __restrict__ scsh, int* __restrict__ bhist) {
  __shared__ int lh[NBUK];
  const int t = threadIdx.x;
  const int i = blockIdx.x * 256 + t;
  if (i < CC * CC) {
    const int k = i >> 7, n = i & 127;
    const int nt = n & 7, m = n >> 3;
    const int kb = k >> 5, q = (k >> 3) & 3, j = k & 7;
    Wsw[(size_t)(((nt * 4 + kb) * 64 + (m + 16 * q)) * 8 + j)] = f2bf(W[i]);
  }
  if (i < CC) {
    const float sc = gamma[i] * rsqrtf(rvar[i] + BN_EPS);
    scsh[i] = sc;
    scsh[CC + i] = beta[i] - rmean[i] * sc;
    scsh[2 * CC + i] = bias[i];
  }
  lh[t] = 0;
  __syncthreads();
  const int e0 = blockIdx.x * ACH;
  const int e1 = min(NE, e0 + ACH);
  for (int e = e0 + t; e < e1; e += 256) atomicAdd(&lh[ei[NE + e] / DPB], 1);
  __syncthreads();
  if (lh[t]) atomicAdd(&bhist[t], lh[t]);
}

// ---------------------------------------------------------------------------
// K2: blocks [0,scat): bucket_scatter — chunk-sort 4096 edges by bucket in
// LDS, reserve contiguous global runs (bhist-scan recomputed in LDS + gcurz
// atomics), write ebuf coalesced. blocks [scat,..): linear_mfma — h =
// bf16(x@W+b), LDS-staged, GROUP-MAJOR h stores: h[(m>>1)*NN*16 + R*16 +
// (m&1)*8 .. +8]. LDS unioned (37KB).
// ---------------------------------------------------------------------------
__global__ __launch_bounds__(256) void scatter_linear(
    const int* __restrict__ ei, const int* __restrict__ bhist,
    int* __restrict__ gcurz, int2* __restrict__ ebuf,
    const float* __restrict__ x, const short* __restrict__ Wsw,
    const float* __restrict__ scsh, short* __restrict__ hout,
    int scat) {
  __shared__ int2 sorted[ACH];  // 32 KB (linear role aliases as bf16 tile)
  __shared__ int gsc[NBUK], lh[NBUK], lex[NBUK], rb[NBUK], lc[NBUK];
  const int t = threadIdx.x;

  if (blockIdx.x < scat) {
    // ----- scatter role -----
    const int e0 = blockIdx.x * ACH;
    const int e1 = min(NE, e0 + ACH);
    // global bucket bases (exclusive scan of bhist)
    const int gbase = excl_scan256(gsc, t, bhist[t]);
    // chunk histogram
    lh[t] = 0;
    __syncthreads();
    for (int e = e0 + t; e < e1; e += 256) atomicAdd(&lh[ei[NE + e] / DPB], 1);
    __syncthreads();
    const int vh = lh[t];
    const int lbase = excl_scan256(lex, t, vh);
    lc[t] = lbase;
    if (vh > 0) rb[t] = gbase + atomicAdd(&gcurz[t], vh);
    __syncthreads();
    // sort chunk into LDS by bucket
    for (int e = e0 + t; e < e1; e += 256) {
      const int src = ei[e], dst = ei[NE + e];
      const int p = atomicAdd(&lc[dst / DPB], 1);
      sorted[p] = make_int2(src, dst);
    }
    __syncthreads();
    // write runs (sequential within each bucket run -> near-full lines)
    const int n = e1 - e0;
    for (int i = t; i < n; i += 256) {
      const int2 v = sorted[i];
      const int b = v.y / DPB;
      ebuf[rb[b] + (i - lex[b])] = v;
    }
    return;
  }

  // ----- linear role -----
  short* lsA = (short*)sorted;  // 64*LSTR*2 = 17.4 KB <= 32 KB
  const int n0 = (blockIdx.x - scat) * 64;

#pragma unroll
  for (int j = 0; j < 8; ++j) {
    const int idx = j * 256 + t;
    const int row = idx >> 5, kc4 = idx & 31;
    float4 v = make_float4(0.f, 0.f, 0.f, 0.f);
    if (n0 + row < NN) v = *(const float4*)(x + (size_t)(n0 + row) * CC + kc4 * 4);
    short4 sv;
    sv.x = f2bf(v.x); sv.y = f2bf(v.y); sv.z = f2bf(v.z); sv.w = f2bf(v.w);
    *(short4*)(lsA + row * LSTR + kc4 * 4) = sv;
  }
  __syncthreads();

  const int wave = t >> 6, lane = t & 63;
  const int quad = lane >> 4, m = lane & 15;
  const int rowbase = n0 + wave * 16;

  f32x4 acc[8];
#pragma unroll
  for (int nt = 0; nt < 8; ++nt) acc[nt] = (f32x4){0.f, 0.f, 0.f, 0.f};

#pragma unroll
  for (int kb = 0; kb < 4; ++kb) {
    const bf16x8 a =
        *(const bf16x8*)(lsA + (wave * 16 + m) * LSTR + kb * 32 + quad * 8);
#pragma unroll
    for (int nt = 0; nt < 8; ++nt) {
      bf16x8 bb = *(const bf16x8*)(Wsw + (size_t)(((nt * 4 + kb) * 64 + lane) * 8));
      acc[nt] = __builtin_amdgcn_mfma_f32_16x16x32_bf16(a, bb, acc[nt], 0, 0, 0);
    }
  }

  const float4 b0 = *(const float4*)(scsh + 2 * CC + m * 8);
  const float4 b1 = *(const float4*)(scsh + 2 * CC + m * 8 + 4);
  const float bv[8] = {b0.x, b0.y, b0.z, b0.w, b1.x, b1.y, b1.z, b1.w};

  // group-major h: lane m covers natural cols m*8..m*8+7, all inside
  // 16-col group (m>>1); sub-half (m&1)*8.
  short* hg = hout + (size_t)(m >> 1) * (NN * 16) + (m & 1) * 8;
#pragma unroll
  for (int reg = 0; reg < 4; ++reg) {
    const int R = rowbase + quad * 4 + reg;
    if (R >= NN) continue;
    bf16x8 hv;
#pragma unroll
    for (int nt = 0; nt < 8; ++nt) hv[nt] = f2bf(acc[nt][reg] + bv[nt]);
    *(bf16x8*)(hg + (size_t)R * 16) = hv;
  }
}

// ---------------------------------------------------------------------------
// K3: one block per bucket. segbase from LDS scan of bhist; per-dst histogram
// + scan -> off[]; scatter srcs into LDS csr segment; coalesced copy-out.
// ---------------------------------------------------------------------------
__global__ __launch_bounds__(256) void bucket_to_csr(
    const int2* __restrict__ ebuf, const int* __restrict__ bhist,
    int* __restrict__ off, int* __restrict__ csr) {
  __shared__ int gs[NBUK];
  __shared__ int dh[512];
  __shared__ int s[512];
  __shared__ int lcur[512];
  __shared__ int lcsr[CAP];  // 40 KB
  const int b = blockIdx.x, t = threadIdx.x;
  excl_scan256(gs, t, bhist[t]);
  const int segbase = gs[b];
  const int seglen = bhist[b];
  const int lo = b * DPB;
  const int hi = min(NN, lo + DPB);
  const int nd = hi - lo;
  const int2* eb = ebuf + segbase;

  for (int i = t; i < 512; i += 256) dh[i] = 0;
  __syncthreads();
  for (int i = t; i < seglen; i += 256) atomicAdd(&dh[eb[i].y - lo], 1);
  __syncthreads();

  for (int i = t; i < 512; i += 256) s[i] = dh[i];
  __syncthreads();
  for (int d = 1; d < 512; d <<= 1) {
    const int a0 = (t >= d) ? s[t - d] : 0;
    const int a1 = (t + 256 >= d) ? s[t + 256 - d] : 0;
    __syncthreads();
    s[t] += a0;
    s[t + 256] += a1;
    __syncthreads();
  }
  for (int i = t; i < 512; i += 256) lcur[i] = s[i] - dh[i];  // exclusive
  for (int d = t; d < nd; d += 256) off[lo + d] = segbase + (s[d] - dh[d]);
  if (b == NBUK - 1 && t == 0) off[NN] = NE;
  __syncthreads();

  if (seglen <= CAP) {
    for (int i = t; i < seglen; i += 256) {
      const int2 e = eb[i];
      const int p = atomicAdd(&lcur[e.y - lo], 1);
      lcsr[p] = e.x;
    }
    __syncthreads();
    for (int i = t; i < seglen; i += 256) csr[segbase + i] = lcsr[i];
  } else {
    for (int i = t; i < seglen; i += 256) {
      const int2 e = eb[i];
      const int p = atomicAdd(&lcur[e.y - lo], 1);
      csr[segbase + p] = e.x;
    }
  }
}

// ---------------------------------------------------------------------------
// K4: XCD-sliced gather. g = blockIdx&7 -> column group (and, via round-robin
// dispatch, XCD). Group slice h[g] is 3.2MB contiguous -> resident in that
// XCD's 4MB L2. Wave = one dst x 16 cols; lane = (e8 edges x c8 uints);
// 2-deep unroll = 16 edges in flight; 3 shfl_xor butterflies reduce e8.
// ---------------------------------------------------------------------------
__global__ __launch_bounds__(256) void gather_bn_relu(
    const short* __restrict__ h, const int* __restrict__ off,
    const int* __restrict__ csr, const float* __restrict__ scsh,
    float* __restrict__ out) {
  const int g = blockIdx.x & 7;  // column group == XCD (bid%8 heuristic)
  const int node = (blockIdx.x >> 3) * 4 + (threadIdx.x >> 6);
  if (node >= NN) return;
  const int lane = threadIdx.x & 63;
  const int e8 = lane >> 3, c8 = lane & 7;
  const int s = off[node], e = off[node + 1];
  const unsigned* hb = (const unsigned*)h + (size_t)g * (NN * 8) + c8;

  float ax = 0.f, ay = 0.f;
  int i = s + e8;
  for (; i + 8 < e; i += 16) {
    const int s0 = csr[i], s1 = csr[i + 8];
    const unsigned p0 = hb[(size_t)s0 * 8];
    const unsigned p1 = hb[(size_t)s1 * 8];
    ax += bflo(p0) + bflo(p1);
    ay += bfhi(p0) + bfhi(p1);
  }
  if (i < e) {
    const unsigned p = hb[(size_t)csr[i] * 8];
    ax += bflo(p);
    ay += bfhi(p);
  }
#pragma unroll
  for (int mask = 8; mask <= 32; mask <<= 1) {
    ax += __shfl_xor(ax, mask);
    ay += __shfl_xor(ay, mask);
  }
  if (e8 == 0) {
    const float inv = (e > s) ? 1.0f / (float)(e - s) : 0.0f;
    const int cidx = g * 16 + c8 * 2;
    const float2 sc = *(const float2*)(scsh + cidx);
    const float2 sh = *(const float2*)(scsh + CC + cidx);
    float2 o;
    o.x = fmaxf(0.f, ax * inv * sc.x + sh.x);
    o.y = fmaxf(0.f, ay * inv * sc.y + sh.y);
    *(float2*)(out + (size_t)node * CC + cidx) = o;
  }
}

// ---------------------------------------------------------------------------
// Fallback (small ws): atomic scatter + fp32 vector GEMM.
// ---------------------------------------------------------------------------
__global__ __launch_bounds__(256) void edge_scatter(
    const float* __restrict__ x, const int* __restrict__ ei,
    float* __restrict__ sums, int* __restrict__ cnt) {
  int gt = blockIdx.x * 256 + threadIdx.x;
  int e = gt >> 5;
  int sub = gt & 31;
  if (e >= NE) return;
  int src = ei[e];
  int dst = ei[NE + e];
  const float4 v = *(const float4*)(x + (size_t)src * CC + sub * 4);
  float* o = sums + (size_t)dst * CC + sub * 4;
  unsafeAtomicAdd(o + 0, v.x);
  unsafeAtomicAdd(o + 1, v.y);
  unsafeAtomicAdd(o + 2, v.z);
  unsafeAtomicAdd(o + 3, v.w);
  if (sub == 0) atomicAdd(cnt + dst, 1);
}

__global__ __launch_bounds__(256) void gemm_bn_relu_fb(
    float* buf, const float* __restrict__ W, const float* __restrict__ bias,
    const float* __restrict__ gamma, const float* __restrict__ beta,
    const float* __restrict__ rmean, const float* __restrict__ rvar,
    const int* __restrict__ cnt) {
  __shared__ float xsT[CC][65];
  const int t = threadIdx.x;
  const int n0 = blockIdx.x * 64;
  for (int j = 0; j < 8; ++j) {
    int i = t + 256 * j;
    int row = i >> 5;
    int ko = (i & 31) * 4;
    float4 v = make_float4(0.f, 0.f, 0.f, 0.f);
    if (n0 + row < NN) v = *(const float4*)(buf + (size_t)(n0 + row) * CC + ko);
    xsT[ko + 0][row] = v.x;
    xsT[ko + 1][row] = v.y;
    xsT[ko + 2][row] = v.z;
    xsT[ko + 3][row] = v.w;
  }
  __syncthreads();
  const int cg = t & 31;
  const int ng8 = (t >> 5) * 8;
  float acc[8][4];
#pragma unroll
  for (int j = 0; j < 8; ++j)
#pragma unroll
    for (int c = 0; c < 4; ++c) acc[j][c] = 0.f;
#pragma unroll 8
  for (int k = 0; k < CC; ++k) {
    const float4 wv = *(const float4*)(W + k * CC + cg * 4);
#pragma unroll
    for (int j = 0; j < 8; ++j) {
      const float xv = xsT[k][ng8 + j];
      acc[j][0] = fmaf(xv, wv.x, acc[j][0]);
      acc[j][1] = fmaf(xv, wv.y, acc[j][1]);
      acc[j][2] = fmaf(xv, wv.z, acc[j][2]);
      acc[j][3] = fmaf(xv, wv.w, acc[j][3]);
    }
  }
  const float4 bb = *(const float4*)(bias + cg * 4);
  const float4 gg = *(const float4*)(gamma + cg * 4);
  const float4 bt = *(const float4*)(beta + cg * 4);
  const float4 mu = *(const float4*)(rmean + cg * 4);
  const float4 vr = *(const float4*)(rvar + cg * 4);
  float sc[4], sh[4];
  sc[0] = gg.x * rsqrtf(vr.x + BN_EPS);
  sc[1] = gg.y * rsqrtf(vr.y + BN_EPS);
  sc[2] = gg.z * rsqrtf(vr.z + BN_EPS);
  sc[3] = gg.w * rsqrtf(vr.w + BN_EPS);
  sh[0] = bt.x - mu.x * sc[0];
  sh[1] = bt.y - mu.y * sc[1];
  sh[2] = bt.z - mu.z * sc[2];
  sh[3] = bt.w - mu.w * sc[3];
#pragma unroll
  for (int j = 0; j < 8; ++j) {
    const int n = n0 + ng8 + j;
    if (n >= NN) continue;
    const int cn = cnt[n];
    const float inv = cn > 0 ? 1.0f / (float)cn : 0.0f;
    const float bsel = cn > 0 ? 1.0f : 0.0f;
    float4 o;
    o.x = fmaxf(0.f, (acc[j][0] * inv + bsel * bb.x) * sc[0] + sh[0]);
    o.y = fmaxf(0.f, (acc[j][1] * inv + bsel * bb.y) * sc[1] + sh[1]);
    o.z = fmaxf(0.f, (acc[j][2] * inv + bsel * bb.z) * sc[2] + sh[2]);
    o.w = fmaxf(0.f, (acc[j][3] * inv + bsel * bb.w) * sc[3] + sh[3]);
    *(float4*)(buf + (size_t)n * CC + cg * 4) = o;
  }
}

extern "C" void kernel_launch(void* const* d_in, const int* in_sizes, int n_in,
                              void* d_out, int out_size, void* d_ws, size_t ws_size,
                              hipStream_t stream) {
  const float* x     = (const float*)d_in[0];
  const int*   ei    = (const int*)d_in[1];
  const float* W     = (const float*)d_in[2];
  const float* bias  = (const float*)d_in[3];
  const float* gamma = (const float*)d_in[4];
  const float* beta  = (const float*)d_in[5];
  const float* rmean = (const float*)d_in[6];
  const float* rvar  = (const float*)d_in[7];
  float* out = (float*)d_out;

  // ws layout (bytes):
  //   off[NN+1] | bhist[256] | gcurz[256] (contiguous -> one 2KB memset)
  //   | csr[NE] | scsh[384f] | Wsw[16384 bf16] | ebuf int2[NE] | h[NN*CC bf16]
  const size_t OFF_B  = 0;
  const size_t BH_B   = 400128;
  const size_t GC_B   = 401152;
  const size_t CSR_B  = 802304;
  const size_t SCSH_B = 7202304;
  const size_t WSW_B  = 7204352;
  const size_t EB_B   = 7237120;
  const size_t H1_B   = 20037120;                     // tier-1 h (after ebuf)
  const size_t NEED1  = H1_B + (size_t)NN * CC * 2;   // 45,637,120
  const size_t NEED2  = EB_B + (size_t)NN * CC * 2;   // 32,837,120 (alias)

  const int GGRID = ((NN + 3) / 4) * 8;  // 25000 node-blocks x 8 col groups

  if (ws_size >= NEED2) {
    int*   off   = (int*)((char*)d_ws + OFF_B);
    int*   bhist = (int*)((char*)d_ws + BH_B);
    int*   gcurz = (int*)((char*)d_ws + GC_B);
    int*   csr   = (int*)((char*)d_ws + CSR_B);
    float* scsh  = (float*)((char*)d_ws + SCSH_B);
    short* Wsw   = (short*)((char*)d_ws + WSW_B);

    hipMemsetAsync(bhist, 0, 2048, stream);  // bhist + gcurz
    prep_hist<<<ABLK, 256, 0, stream>>>(W, bias, gamma, beta, rmean, rvar,
                                        ei, Wsw, scsh, bhist);
    if (ws_size >= NEED1) {
      // tier 1: fused scatter+linear (ebuf and h distinct)
      int2*  ebuf = (int2*)((char*)d_ws + EB_B);
      short* h    = (short*)((char*)d_ws + H1_B);
      scatter_linear<<<ABLK + LBLK, 256, 0, stream>>>(
          ei, bhist, gcurz, ebuf, x, Wsw, scsh, h, ABLK);
      bucket_to_csr<<<NBUK, 256, 0, stream>>>(ebuf, bhist, off, csr);
      gather_bn_relu<<<GGRID, 256, 0, stream>>>(h, off, csr, scsh, out);
    } else {
      // tier 2: un-fused, ebuf aliases h (r8-proven ordering)
      int2*  ebuf = (int2*)((char*)d_ws + EB_B);
      short* h    = (short*)((char*)d_ws + EB_B);
      scatter_linear<<<ABLK, 256, 0, stream>>>(
          ei, bhist, gcurz, ebuf, x, Wsw, scsh, h, ABLK);  // scatter only
      bucket_to_csr<<<NBUK, 256, 0, stream>>>(ebuf, bhist, off, csr);
      scatter_linear<<<LBLK, 256, 0, stream>>>(
          ei, bhist, gcurz, ebuf, x, Wsw, scsh, h, 0);     // linear only
      gather_bn_relu<<<GGRID, 256, 0, stream>>>(h, off, csr, scsh, out);
    }
  } else {
    int* cnt = (int*)d_ws;
    hipMemsetAsync(out, 0, (size_t)NN * CC * sizeof(float), stream);
    hipMemsetAsync(cnt, 0, (size_t)NN * sizeof(int), stream);
    edge_scatter<<<(NE * 32) / 256, 256, 0, stream>>>(x, ei, out, cnt);
    gemm_bn_relu_fb<<<(NN + 63) / 64, 256, 0, stream>>>(
        out, W, bias, gamma, beta, rmean, rvar, cnt);
  }
}

// Round 2
// 255.320 us; speedup vs baseline: 1.5228x; 1.5228x over previous
//
#include <hip/hip_runtime.h>

// GCN layer on MI355X — round 11: octet gather (XCD-sliced, low-overhead).
//   M1:  memsetAsync(bhist+gcurz, 0, 2KB)
//   K1 prep_hist:      Wsw swizzle + BN consts (blocks 0-63) FUSED with
//                      bucket histogram (all 391 blocks)
//   K2 scatter_linear: bucket_scatter (391 blocks) FUSED with linear_mfma
//                      (1563 blocks). Linear stores h GROUP-MAJOR:
//                      h[g][node][16 cols] bf16 (3.2MB per group slice).
//   K3 bucket_to_csr:  widened to 1024 threads/block (was 256 -> 12.5% occ);
//                      same per-bucket LDS algorithm, 4x parallelism.
//   K4 gather_bn_relu: octet gather. g = blockIdx&7 -> column group pinned
//                      to one XCD (round-robin heuristic, PROVEN r10: FETCH
//                      179->61MB). Wave = 8 nodes x 8 uint-cols; each lane
//                      owns (node,col) fully -> NO shuffle epilogue; 4-deep
//                      edge unroll; wave count back to 100k (r10 was 800k,
//                      which was the regression: per-wave overhead x8).
// Fusion forces ebuf != h  -> NEED 45.6MB; tier-2 (ws >= 32.8MB) runs the
// same kernels un-fused with ebuf aliasing h; atomic fallback last.
// mean(h[src]) = mean(x[src])@W + b (linearity); deg=0 -> sum=0 -> relu(sh).

#define NN 100000
#define NE 1600000
#define CC 128
#define BN_EPS 1e-5f
#define LBLK 1563     // ceil(NN/64) linear blocks
#define LSTR 136      // LDS row stride in bf16 (128 + 8 pad)
#define NBUK 256      // dst buckets
#define DPB 391       // dsts per bucket (256*391 = 100096 >= NN)
#define ACH 4096      // edges per scatter block
#define ABLK 391      // ceil(NE/ACH)
#define CAP 10240     // to_csr LDS segment capacity (mean 6250, huge margin)

typedef __attribute__((ext_vector_type(8))) short bf16x8;
typedef __attribute__((ext_vector_type(4))) float f32x4;

static __device__ __forceinline__ short f2bf(float f) {
  union { float f; unsigned u; } v; v.f = f;
  unsigned r = (v.u + 0x7FFF + ((v.u >> 16) & 1)) >> 16;  // RNE
  return (short)r;
}
static __device__ __forceinline__ float bflo(unsigned p) {
  return __uint_as_float(p << 16);
}
static __device__ __forceinline__ float bfhi(unsigned p) {
  return __uint_as_float(p & 0xffff0000u);
}

// 256-wide Hillis-Steele scan in LDS; leaves a[] exclusive, returns excl[t].
// (256-thread blocks only.)
static __device__ __forceinline__ int excl_scan256(int* a, int t, int v) {
  a[t] = v;
  __syncthreads();
  for (int d = 1; d < 256; d <<= 1) {
    const int x = (t >= d) ? a[t - d] : 0;
    __syncthreads();
    a[t] += x;
    __syncthreads();
  }
  const int incl = a[t];
  __syncthreads();
  a[t] = incl - v;
  __syncthreads();
  return incl - v;
}

// ---------------------------------------------------------------------------
// K1: prep (Wsw swizzle, col-permuted so D-lane m holds natural cols m*8..+7;
// BN scale/shift + bias) on blocks 0-63, bucket histogram on all 391 blocks.
// bhist pre-zeroed by the M1 memset.
// ---------------------------------------------------------------------------
__global__ __launch_bounds__(256) void prep_hist(
    const float* __restrict__ W, const float* __restrict__ bias,
    const float* __restrict__ gamma, const float* __restrict__ beta,
    const float* __restrict__ rmean, const float* __restrict__ rvar,
    const int* __restrict__ ei, short* __restrict__ Wsw,
    float* __restrict__ scsh, int* __restrict__ bhist) {
  __shared__ int lh[NBUK];
  const int t = threadIdx.x;
  const int i = blockIdx.x * 256 + t;
  if (i < CC * CC) {
    const int k = i >> 7, n = i & 127;
    const int nt = n & 7, m = n >> 3;
    const int kb = k >> 5, q = (k >> 3) & 3, j = k & 7;
    Wsw[(size_t)(((nt * 4 + kb) * 64 + (m + 16 * q)) * 8 + j)] = f2bf(W[i]);
  }
  if (i < CC) {
    const float sc = gamma[i] * rsqrtf(rvar[i] + BN_EPS);
    scsh[i] = sc;
    scsh[CC + i] = beta[i] - rmean[i] * sc;
    scsh[2 * CC + i] = bias[i];
  }
  lh[t] = 0;
  __syncthreads();
  const int e0 = blockIdx.x * ACH;
  const int e1 = min(NE, e0 + ACH);
  for (int e = e0 + t; e < e1; e += 256) atomicAdd(&lh[ei[NE + e] / DPB], 1);
  __syncthreads();
  if (lh[t]) atomicAdd(&bhist[t], lh[t]);
}

// ---------------------------------------------------------------------------
// K2: blocks [0,scat): bucket_scatter — chunk-sort 4096 edges by bucket in
// LDS, reserve contiguous global runs (bhist-scan recomputed in LDS + gcurz
// atomics), write ebuf coalesced. blocks [scat,..): linear_mfma — h =
// bf16(x@W+b), LDS-staged, GROUP-MAJOR h stores. LDS unioned (37KB).
// ---------------------------------------------------------------------------
__global__ __launch_bounds__(256) void scatter_linear(
    const int* __restrict__ ei, const int* __restrict__ bhist,
    int* __restrict__ gcurz, int2* __restrict__ ebuf,
    const float* __restrict__ x, const short* __restrict__ Wsw,
    const float* __restrict__ scsh, short* __restrict__ hout,
    int scat) {
  __shared__ int2 sorted[ACH];  // 32 KB (linear role aliases as bf16 tile)
  __shared__ int gsc[NBUK], lh[NBUK], lex[NBUK], rb[NBUK], lc[NBUK];
  const int t = threadIdx.x;

  if (blockIdx.x < scat) {
    // ----- scatter role -----
    const int e0 = blockIdx.x * ACH;
    const int e1 = min(NE, e0 + ACH);
    // global bucket bases (exclusive scan of bhist)
    const int gbase = excl_scan256(gsc, t, bhist[t]);
    // chunk histogram
    lh[t] = 0;
    __syncthreads();
    for (int e = e0 + t; e < e1; e += 256) atomicAdd(&lh[ei[NE + e] / DPB], 1);
    __syncthreads();
    const int vh = lh[t];
    const int lbase = excl_scan256(lex, t, vh);
    lc[t] = lbase;
    if (vh > 0) rb[t] = gbase + atomicAdd(&gcurz[t], vh);
    __syncthreads();
    // sort chunk into LDS by bucket
    for (int e = e0 + t; e < e1; e += 256) {
      const int src = ei[e], dst = ei[NE + e];
      const int p = atomicAdd(&lc[dst / DPB], 1);
      sorted[p] = make_int2(src, dst);
    }
    __syncthreads();
    // write runs (sequential within each bucket run -> near-full lines)
    const int n = e1 - e0;
    for (int i = t; i < n; i += 256) {
      const int2 v = sorted[i];
      const int b = v.y / DPB;
      ebuf[rb[b] + (i - lex[b])] = v;
    }
    return;
  }

  // ----- linear role -----
  short* lsA = (short*)sorted;  // 64*LSTR*2 = 17.4 KB <= 32 KB
  const int n0 = (blockIdx.x - scat) * 64;

#pragma unroll
  for (int j = 0; j < 8; ++j) {
    const int idx = j * 256 + t;
    const int row = idx >> 5, kc4 = idx & 31;
    float4 v = make_float4(0.f, 0.f, 0.f, 0.f);
    if (n0 + row < NN) v = *(const float4*)(x + (size_t)(n0 + row) * CC + kc4 * 4);
    short4 sv;
    sv.x = f2bf(v.x); sv.y = f2bf(v.y); sv.z = f2bf(v.z); sv.w = f2bf(v.w);
    *(short4*)(lsA + row * LSTR + kc4 * 4) = sv;
  }
  __syncthreads();

  const int wave = t >> 6, lane = t & 63;
  const int quad = lane >> 4, m = lane & 15;
  const int rowbase = n0 + wave * 16;

  f32x4 acc[8];
#pragma unroll
  for (int nt = 0; nt < 8; ++nt) acc[nt] = (f32x4){0.f, 0.f, 0.f, 0.f};

#pragma unroll
  for (int kb = 0; kb < 4; ++kb) {
    const bf16x8 a =
        *(const bf16x8*)(lsA + (wave * 16 + m) * LSTR + kb * 32 + quad * 8);
#pragma unroll
    for (int nt = 0; nt < 8; ++nt) {
      bf16x8 bb = *(const bf16x8*)(Wsw + (size_t)(((nt * 4 + kb) * 64 + lane) * 8));
      acc[nt] = __builtin_amdgcn_mfma_f32_16x16x32_bf16(a, bb, acc[nt], 0, 0, 0);
    }
  }

  const float4 b0 = *(const float4*)(scsh + 2 * CC + m * 8);
  const float4 b1 = *(const float4*)(scsh + 2 * CC + m * 8 + 4);
  const float bv[8] = {b0.x, b0.y, b0.z, b0.w, b1.x, b1.y, b1.z, b1.w};

  // group-major h: lane m covers natural cols m*8..m*8+7, all inside
  // 16-col group (m>>1); sub-half (m&1)*8.
  short* hg = hout + (size_t)(m >> 1) * (NN * 16) + (m & 1) * 8;
#pragma unroll
  for (int reg = 0; reg < 4; ++reg) {
    const int R = rowbase + quad * 4 + reg;
    if (R >= NN) continue;
    bf16x8 hv;
#pragma unroll
    for (int nt = 0; nt < 8; ++nt) hv[nt] = f2bf(acc[nt][reg] + bv[nt]);
    *(bf16x8*)(hg + (size_t)R * 16) = hv;
  }
}

// ---------------------------------------------------------------------------
// K3: one 1024-thread block per bucket (was 256: 1 block/CU at 4 waves ->
// latency-bound; now 16 waves/CU). segbase from LDS scan of bhist; per-dst
// histogram + scan -> off[]; scatter srcs into LDS csr segment; coalesced
// copy-out. All barriers executed by all 1024 threads.
// ---------------------------------------------------------------------------
__global__ __launch_bounds__(1024) void bucket_to_csr(
    const int2* __restrict__ ebuf, const int* __restrict__ bhist,
    int* __restrict__ off, int* __restrict__ csr) {
  __shared__ int gs[NBUK];
  __shared__ int dh[512];
  __shared__ int s[512];
  __shared__ int lcur[512];
  __shared__ int lcsr[CAP];  // 40 KB
  const int b = blockIdx.x, t = threadIdx.x;

  // inclusive scan of bhist into gs (threads >= NBUK just hit barriers)
  if (t < NBUK) gs[t] = bhist[t];
  __syncthreads();
  for (int d = 1; d < NBUK; d <<= 1) {
    int a0 = 0;
    if (t < NBUK && t >= d) a0 = gs[t - d];
    __syncthreads();
    if (t < NBUK) gs[t] += a0;
    __syncthreads();
  }
  const int seglen = bhist[b];
  const int segbase = gs[b] - seglen;
  const int lo = b * DPB;
  const int hi = min(NN, lo + DPB);
  const int nd = hi - lo;
  const int2* eb = ebuf + segbase;

  if (t < 512) dh[t] = 0;
  __syncthreads();
  for (int i = t; i < seglen; i += 1024) atomicAdd(&dh[eb[i].y - lo], 1);
  __syncthreads();

  if (t < 512) s[t] = dh[t];
  __syncthreads();
  for (int d = 1; d < 512; d <<= 1) {
    int a0 = 0;
    if (t < 512 && t >= d) a0 = s[t - d];
    __syncthreads();
    if (t < 512) s[t] += a0;
    __syncthreads();
  }
  if (t < 512) lcur[t] = s[t] - dh[t];  // exclusive
  if (t < nd) off[lo + t] = segbase + (s[t] - dh[t]);
  if (b == NBUK - 1 && t == 0) off[NN] = NE;
  __syncthreads();

  if (seglen <= CAP) {
    for (int i = t; i < seglen; i += 1024) {
      const int2 e = eb[i];
      const int p = atomicAdd(&lcur[e.y - lo], 1);
      lcsr[p] = e.x;
    }
    __syncthreads();
    for (int i = t; i < seglen; i += 1024) csr[segbase + i] = lcsr[i];
  } else {
    for (int i = t; i < seglen; i += 1024) {
      const int2 e = eb[i];
      const int p = atomicAdd(&lcur[e.y - lo], 1);
      csr[segbase + p] = e.x;
    }
  }
}

// ---------------------------------------------------------------------------
// K4: octet gather. g = blockIdx&7 -> column group == XCD (round-robin
// heuristic; r10 proved FETCH 179->61MB with this mapping). Wave = 8 nodes x
// 8 uint-cols: lane owns (node, 2 natural cols) fully, accumulates ALL its
// node's edges sequentially -> no cross-lane reduce. 4-deep unroll = 8
// independent h-loads in flight per lane-row. Octet-uniform csr addresses
// broadcast. 100k waves total (r10's regression was 800k waves).
// ---------------------------------------------------------------------------
__global__ __launch_bounds__(256) void gather_bn_relu(
    const short* __restrict__ h, const int* __restrict__ off,
    const int* __restrict__ csr, const float* __restrict__ scsh,
    float* __restrict__ out) {
  const int g = blockIdx.x & 7;  // column group == XCD (bid%8 heuristic)
  const int wave = threadIdx.x >> 6, lane = threadIdx.x & 63;
  const int o = lane >> 3, c8 = lane & 7;
  const int node = (blockIdx.x >> 3) * 32 + wave * 8 + o;  // 3125*32 == NN
  const unsigned* hb = (const unsigned*)h + (size_t)g * (NN * 8) + c8;

  int s = 0, e = 0;
  if (node < NN) { s = off[node]; e = off[node + 1]; }

  float ax = 0.f, ay = 0.f;
  int i = s;
  for (; i + 4 <= e; i += 4) {
    const int s0 = csr[i + 0], s1 = csr[i + 1];
    const int s2 = csr[i + 2], s3 = csr[i + 3];
    const unsigned p0 = hb[(size_t)s0 * 8];
    const unsigned p1 = hb[(size_t)s1 * 8];
    const unsigned p2 = hb[(size_t)s2 * 8];
    const unsigned p3 = hb[(size_t)s3 * 8];
    ax += (bflo(p0) + bflo(p1)) + (bflo(p2) + bflo(p3));
    ay += (bfhi(p0) + bfhi(p1)) + (bfhi(p2) + bfhi(p3));
  }
  for (; i < e; ++i) {
    const unsigned p = hb[(size_t)csr[i] * 8];
    ax += bflo(p);
    ay += bfhi(p);
  }
  if (node < NN) {
    const float inv = (e > s) ? 1.0f / (float)(e - s) : 0.0f;
    const int cidx = g * 16 + c8 * 2;
    const float2 sc = *(const float2*)(scsh + cidx);
    const float2 sh = *(const float2*)(scsh + CC + cidx);
    float2 o2;
    o2.x = fmaxf(0.f, ax * inv * sc.x + sh.x);
    o2.y = fmaxf(0.f, ay * inv * sc.y + sh.y);
    *(float2*)(out + (size_t)node * CC + cidx) = o2;
  }
}

// ---------------------------------------------------------------------------
// Fallback (small ws): atomic scatter + fp32 vector GEMM.
// ---------------------------------------------------------------------------
__global__ __launch_bounds__(256) void edge_scatter(
    const float* __restrict__ x, const int* __restrict__ ei,
    float* __restrict__ sums, int* __restrict__ cnt) {
  int gt = blockIdx.x * 256 + threadIdx.x;
  int e = gt >> 5;
  int sub = gt & 31;
  if (e >= NE) return;
  int src = ei[e];
  int dst = ei[NE + e];
  const float4 v = *(const float4*)(x + (size_t)src * CC + sub * 4);
  float* o = sums + (size_t)dst * CC + sub * 4;
  unsafeAtomicAdd(o + 0, v.x);
  unsafeAtomicAdd(o + 1, v.y);
  unsafeAtomicAdd(o + 2, v.z);
  unsafeAtomicAdd(o + 3, v.w);
  if (sub == 0) atomicAdd(cnt + dst, 1);
}

__global__ __launch_bounds__(256) void gemm_bn_relu_fb(
    float* buf, const float* __restrict__ W, const float* __restrict__ bias,
    const float* __restrict__ gamma, const float* __restrict__ beta,
    const float* __restrict__ rmean, const float* __restrict__ rvar,
    const int* __restrict__ cnt) {
  __shared__ float xsT[CC][65];
  const int t = threadIdx.x;
  const int n0 = blockIdx.x * 64;
  for (int j = 0; j < 8; ++j) {
    int i = t + 256 * j;
    int row = i >> 5;
    int ko = (i & 31) * 4;
    float4 v = make_float4(0.f, 0.f, 0.f, 0.f);
    if (n0 + row < NN) v = *(const float4*)(buf + (size_t)(n0 + row) * CC + ko);
    xsT[ko + 0][row] = v.x;
    xsT[ko + 1][row] = v.y;
    xsT[ko + 2][row] = v.z;
    xsT[ko + 3][row] = v.w;
  }
  __syncthreads();
  const int cg = t & 31;
  const int ng8 = (t >> 5) * 8;
  float acc[8][4];
#pragma unroll
  for (int j = 0; j < 8; ++j)
#pragma unroll
    for (int c = 0; c < 4; ++c) acc[j][c] = 0.f;
#pragma unroll 8
  for (int k = 0; k < CC; ++k) {
    const float4 wv = *(const float4*)(W + k * CC + cg * 4);
#pragma unroll
    for (int j = 0; j < 8; ++j) {
      const float xv = xsT[k][ng8 + j];
      acc[j][0] = fmaf(xv, wv.x, acc[j][0]);
      acc[j][1] = fmaf(xv, wv.y, acc[j][1]);
      acc[j][2] = fmaf(xv, wv.z, acc[j][2]);
      acc[j][3] = fmaf(xv, wv.w, acc[j][3]);
    }
  }
  const float4 bb = *(const float4*)(bias + cg * 4);
  const float4 gg = *(const float4*)(gamma + cg * 4);
  const float4 bt = *(const float4*)(beta + cg * 4);
  const float4 mu = *(const float4*)(rmean + cg * 4);
  const float4 vr = *(const float4*)(rvar + cg * 4);
  float sc[4], sh[4];
  sc[0] = gg.x * rsqrtf(vr.x + BN_EPS);
  sc[1] = gg.y * rsqrtf(vr.y + BN_EPS);
  sc[2] = gg.z * rsqrtf(vr.z + BN_EPS);
  sc[3] = gg.w * rsqrtf(vr.w + BN_EPS);
  sh[0] = bt.x - mu.x * sc[0];
  sh[1] = bt.y - mu.y * sc[1];
  sh[2] = bt.z - mu.z * sc[2];
  sh[3] = bt.w - mu.w * sc[3];
#pragma unroll
  for (int j = 0; j < 8; ++j) {
    const int n = n0 + ng8 + j;
    if (n >= NN) continue;
    const int cn = cnt[n];
    const float inv = cn > 0 ? 1.0f / (float)cn : 0.0f;
    const float bsel = cn > 0 ? 1.0f : 0.0f;
    float4 o;
    o.x = fmaxf(0.f, (acc[j][0] * inv + bsel * bb.x) * sc[0] + sh[0]);
    o.y = fmaxf(0.f, (acc[j][1] * inv + bsel * bb.y) * sc[1] + sh[1]);
    o.z = fmaxf(0.f, (acc[j][2] * inv + bsel * bb.z) * sc[2] + sh[2]);
    o.w = fmaxf(0.f, (acc[j][3] * inv + bsel * bb.w) * sc[3] + sh[3]);
    *(float4*)(buf + (size_t)n * CC + cg * 4) = o;
  }
}

extern "C" void kernel_launch(void* const* d_in, const int* in_sizes, int n_in,
                              void* d_out, int out_size, void* d_ws, size_t ws_size,
                              hipStream_t stream) {
  const float* x     = (const float*)d_in[0];
  const int*   ei    = (const int*)d_in[1];
  const float* W     = (const float*)d_in[2];
  const float* bias  = (const float*)d_in[3];
  const float* gamma = (const float*)d_in[4];
  const float* beta  = (const float*)d_in[5];
  const float* rmean = (const float*)d_in[6];
  const float* rvar  = (const float*)d_in[7];
  float* out = (float*)d_out;

  // ws layout (bytes):
  //   off[NN+1] | bhist[256] | gcurz[256] (contiguous -> one 2KB memset)
  //   | csr[NE] | scsh[384f] | Wsw[16384 bf16] | ebuf int2[NE] | h[NN*CC bf16]
  const size_t OFF_B  = 0;
  const size_t BH_B   = 400128;
  const size_t GC_B   = 401152;
  const size_t CSR_B  = 802304;
  const size_t SCSH_B = 7202304;
  const size_t WSW_B  = 7204352;
  const size_t EB_B   = 7237120;
  const size_t H1_B   = 20037120;                     // tier-1 h (after ebuf)
  const size_t NEED1  = H1_B + (size_t)NN * CC * 2;   // 45,637,120
  const size_t NEED2  = EB_B + (size_t)NN * CC * 2;   // 32,837,120 (alias)

  const int GGRID = ((NN + 31) / 32) * 8;  // 3125 node-blocks x 8 col groups

  if (ws_size >= NEED2) {
    int*   off   = (int*)((char*)d_ws + OFF_B);
    int*   bhist = (int*)((char*)d_ws + BH_B);
    int*   gcurz = (int*)((char*)d_ws + GC_B);
    int*   csr   = (int*)((char*)d_ws + CSR_B);
    float* scsh  = (float*)((char*)d_ws + SCSH_B);
    short* Wsw   = (short*)((char*)d_ws + WSW_B);

    hipMemsetAsync(bhist, 0, 2048, stream);  // bhist + gcurz
    prep_hist<<<ABLK, 256, 0, stream>>>(W, bias, gamma, beta, rmean, rvar,
                                        ei, Wsw, scsh, bhist);
    if (ws_size >= NEED1) {
      // tier 1: fused scatter+linear (ebuf and h distinct)
      int2*  ebuf = (int2*)((char*)d_ws + EB_B);
      short* h    = (short*)((char*)d_ws + H1_B);
      scatter_linear<<<ABLK + LBLK, 256, 0, stream>>>(
          ei, bhist, gcurz, ebuf, x, Wsw, scsh, h, ABLK);
      bucket_to_csr<<<NBUK, 1024, 0, stream>>>(ebuf, bhist, off, csr);
      gather_bn_relu<<<GGRID, 256, 0, stream>>>(h, off, csr, scsh, out);
    } else {
      // tier 2: un-fused, ebuf aliases h (r8-proven ordering)
      int2*  ebuf = (int2*)((char*)d_ws + EB_B);
      short* h    = (short*)((char*)d_ws + EB_B);
      scatter_linear<<<ABLK, 256, 0, stream>>>(
          ei, bhist, gcurz, ebuf, x, Wsw, scsh, h, ABLK);  // scatter only
      bucket_to_csr<<<NBUK, 1024, 0, stream>>>(ebuf, bhist, off, csr);
      scatter_linear<<<LBLK, 256, 0, stream>>>(
          ei, bhist, gcurz, ebuf, x, Wsw, scsh, h, 0);     // linear only
      gather_bn_relu<<<GGRID, 256, 0, stream>>>(h, off, csr, scsh, out);
    }
  } else {
    int* cnt = (int*)d_ws;
    hipMemsetAsync(out, 0, (size_t)NN * CC * sizeof(float), stream);
    hipMemsetAsync(cnt, 0, (size_t)NN * sizeof(int), stream);
    edge_scatter<<<(NE * 32) / 256, 256, 0, stream>>>(x, ei, out, cnt);
    gemm_bn_relu_fb<<<(NN + 63) / 64, 256, 0, stream>>>(
        out, W, bias, gamma, beta, rmean, rvar, cnt);
  }
}

// Round 3
// 238.669 us; speedup vs baseline: 1.6291x; 1.0698x over previous
//
#include <hip/hip_runtime.h>

// GCN layer on MI355X — round 12: LDS-csr gather (VMEM-instruction diet).
//   M1:  memsetAsync(bhist+gcurz, 0, 2KB)
//   K1 prep_hist:      Wsw swizzle + BN consts (blocks 0-63) FUSED with
//                      bucket histogram (all 391 blocks)
//   K2 scatter_linear: bucket_scatter (391) FUSED with linear_mfma (1563).
//                      h GROUP-MAJOR [8][NN][16] bf16; NEW: output tile
//                      staged in LDS then stored as 2KB-contiguous per-group
//                      runs (r11 stored a 64x16B scatter per instr).
//   K3 bucket_to_csr:  1024 threads/block.
//   K4 gather_bn_relu: block = 256 nodes x 1 col-group (g = bid&7 -> XCD,
//                      PROVEN: FETCH 179->87MB). csr segment for the block's
//                      nodes is CONTIGUOUS (csr globally dst-sorted) ->
//                      staged to LDS once, coalesced; edge loop reads csr
//                      from LDS (LGKM pipe) + ONE uint2 (8B) h load per
//                      edge per lane (4 lanes/node). VMEM instrs drop ~4x
//                      vs r11 (was 19cy/instr issue-bound at 98.5us).
//                      Each 4-lane group owns 4 sequential nodes (78%
//                      divergence efficiency vs 70%).
// Fusion forces ebuf != h  -> NEED 45.6MB; tier-2 (ws >= 32.8MB) runs the
// same kernels un-fused with ebuf aliasing h; atomic fallback last.
// mean(h[src]) = mean(x[src])@W + b (linearity); deg=0 -> sum=0 -> relu(sh).

#define NN 100000
#define NE 1600000
#define CC 128
#define BN_EPS 1e-5f
#define LBLK 1563     // ceil(NN/64) linear blocks
#define LSTR 136      // LDS row stride in bf16 (128 + 8 pad)
#define NBUK 256      // dst buckets
#define DPB 391       // dsts per bucket (256*391 = 100096 >= NN)
#define ACH 4096      // edges per scatter block
#define ABLK 391      // ceil(NE/ACH)
#define CAP 10240     // to_csr LDS segment capacity (mean 6250, huge margin)
#define GNB 256       // nodes per gather block
#define CAP2 5120     // gather csr LDS capacity (mean 4096, std 64: +16sigma)

typedef __attribute__((ext_vector_type(8))) short bf16x8;
typedef __attribute__((ext_vector_type(4))) float f32x4;

static __device__ __forceinline__ short f2bf(float f) {
  union { float f; unsigned u; } v; v.f = f;
  unsigned r = (v.u + 0x7FFF + ((v.u >> 16) & 1)) >> 16;  // RNE
  return (short)r;
}
static __device__ __forceinline__ float bflo(unsigned p) {
  return __uint_as_float(p << 16);
}
static __device__ __forceinline__ float bfhi(unsigned p) {
  return __uint_as_float(p & 0xffff0000u);
}

// 256-wide Hillis-Steele scan in LDS; leaves a[] exclusive, returns excl[t].
// (256-thread blocks only.)
static __device__ __forceinline__ int excl_scan256(int* a, int t, int v) {
  a[t] = v;
  __syncthreads();
  for (int d = 1; d < 256; d <<= 1) {
    const int x = (t >= d) ? a[t - d] : 0;
    __syncthreads();
    a[t] += x;
    __syncthreads();
  }
  const int incl = a[t];
  __syncthreads();
  a[t] = incl - v;
  __syncthreads();
  return incl - v;
}

// ---------------------------------------------------------------------------
// K1: prep (Wsw swizzle, col-permuted so D-lane m holds natural cols m*8..+7;
// BN scale/shift + bias) on blocks 0-63, bucket histogram on all 391 blocks.
// bhist pre-zeroed by the M1 memset.
// ---------------------------------------------------------------------------
__global__ __launch_bounds__(256) void prep_hist(
    const float* __restrict__ W, const float* __restrict__ bias,
    const float* __restrict__ gamma, const float* __restrict__ beta,
    const float* __restrict__ rmean, const float* __restrict__ rvar,
    const int* __restrict__ ei, short* __restrict__ Wsw,
    float* __restrict__ scsh, int* __restrict__ bhist) {
  __shared__ int lh[NBUK];
  const int t = threadIdx.x;
  const int i = blockIdx.x * 256 + t;
  if (i < CC * CC) {
    const int k = i >> 7, n = i & 127;
    const int nt = n & 7, m = n >> 3;
    const int kb = k >> 5, q = (k >> 3) & 3, j = k & 7;
    Wsw[(size_t)(((nt * 4 + kb) * 64 + (m + 16 * q)) * 8 + j)] = f2bf(W[i]);
  }
  if (i < CC) {
    const float sc = gamma[i] * rsqrtf(rvar[i] + BN_EPS);
    scsh[i] = sc;
    scsh[CC + i] = beta[i] - rmean[i] * sc;
    scsh[2 * CC + i] = bias[i];
  }
  lh[t] = 0;
  __syncthreads();
  const int e0 = blockIdx.x * ACH;
  const int e1 = min(NE, e0 + ACH);
  for (int e = e0 + t; e < e1; e += 256) atomicAdd(&lh[ei[NE + e] / DPB], 1);
  __syncthreads();
  if (lh[t]) atomicAdd(&bhist[t], lh[t]);
}

// ---------------------------------------------------------------------------
// K2: blocks [0,scat): bucket_scatter — chunk-sort 4096 edges by bucket in
// LDS, reserve contiguous global runs, write ebuf coalesced. blocks
// [scat,..): linear_mfma — h = bf16(x@W+b), LDS-staged input, MFMA, then
// output tile re-staged in LDS and stored as per-group contiguous runs.
// ---------------------------------------------------------------------------
__global__ __launch_bounds__(256) void scatter_linear(
    const int* __restrict__ ei, const int* __restrict__ bhist,
    int* __restrict__ gcurz, int2* __restrict__ ebuf,
    const float* __restrict__ x, const short* __restrict__ Wsw,
    const float* __restrict__ scsh, short* __restrict__ hout,
    int scat) {
  __shared__ int2 sorted[ACH];  // 32 KB (linear role aliases as bf16 tile)
  __shared__ int gsc[NBUK], lh[NBUK], lex[NBUK], rb[NBUK], lc[NBUK];
  const int t = threadIdx.x;

  if (blockIdx.x < scat) {
    // ----- scatter role -----
    const int e0 = blockIdx.x * ACH;
    const int e1 = min(NE, e0 + ACH);
    const int gbase = excl_scan256(gsc, t, bhist[t]);
    lh[t] = 0;
    __syncthreads();
    for (int e = e0 + t; e < e1; e += 256) atomicAdd(&lh[ei[NE + e] / DPB], 1);
    __syncthreads();
    const int vh = lh[t];
    const int lbase = excl_scan256(lex, t, vh);
    lc[t] = lbase;
    if (vh > 0) rb[t] = gbase + atomicAdd(&gcurz[t], vh);
    __syncthreads();
    for (int e = e0 + t; e < e1; e += 256) {
      const int src = ei[e], dst = ei[NE + e];
      const int p = atomicAdd(&lc[dst / DPB], 1);
      sorted[p] = make_int2(src, dst);
    }
    __syncthreads();
    const int n = e1 - e0;
    for (int i = t; i < n; i += 256) {
      const int2 v = sorted[i];
      const int b = v.y / DPB;
      ebuf[rb[b] + (i - lex[b])] = v;
    }
    return;
  }

  // ----- linear role -----
  short* lsA = (short*)sorted;  // 64*LSTR*2 = 17.4 KB <= 32 KB
  const int n0 = (blockIdx.x - scat) * 64;

#pragma unroll
  for (int j = 0; j < 8; ++j) {
    const int idx = j * 256 + t;
    const int row = idx >> 5, kc4 = idx & 31;
    float4 v = make_float4(0.f, 0.f, 0.f, 0.f);
    if (n0 + row < NN) v = *(const float4*)(x + (size_t)(n0 + row) * CC + kc4 * 4);
    short4 sv;
    sv.x = f2bf(v.x); sv.y = f2bf(v.y); sv.z = f2bf(v.z); sv.w = f2bf(v.w);
    *(short4*)(lsA + row * LSTR + kc4 * 4) = sv;
  }
  __syncthreads();

  const int wave = t >> 6, lane = t & 63;
  const int quad = lane >> 4, m = lane & 15;

  f32x4 acc[8];
#pragma unroll
  for (int nt = 0; nt < 8; ++nt) acc[nt] = (f32x4){0.f, 0.f, 0.f, 0.f};

#pragma unroll
  for (int kb = 0; kb < 4; ++kb) {
    const bf16x8 a =
        *(const bf16x8*)(lsA + (wave * 16 + m) * LSTR + kb * 32 + quad * 8);
#pragma unroll
    for (int nt = 0; nt < 8; ++nt) {
      bf16x8 bb = *(const bf16x8*)(Wsw + (size_t)(((nt * 4 + kb) * 64 + lane) * 8));
      acc[nt] = __builtin_amdgcn_mfma_f32_16x16x32_bf16(a, bb, acc[nt], 0, 0, 0);
    }
  }

  const float4 b0 = *(const float4*)(scsh + 2 * CC + m * 8);
  const float4 b1 = *(const float4*)(scsh + 2 * CC + m * 8 + 4);
  const float bv[8] = {b0.x, b0.y, b0.z, b0.w, b1.x, b1.y, b1.z, b1.w};

  __syncthreads();  // all A-tile reads done; reuse lsA for the output tile

  // stage bf16 output tile [64][LSTR]: lane m holds natural cols m*8..+7
#pragma unroll
  for (int reg = 0; reg < 4; ++reg) {
    const int r = wave * 16 + quad * 4 + reg;  // local row 0..63
    bf16x8 hv;
#pragma unroll
    for (int nt = 0; nt < 8; ++nt) hv[nt] = f2bf(acc[nt][reg] + bv[nt]);
    *(bf16x8*)(lsA + r * LSTR + m * 8) = hv;
  }
  __syncthreads();

  // copy out: per group g, rows of 16 bf16 are contiguous in h[g][node][16]
  // -> 2KB contiguous runs. 2 groups per round, 128 threads per group.
#pragma unroll
  for (int rr = 0; rr < 4; ++rr) {
    const int g2 = rr * 2 + (t >> 7);
    const int idx = t & 127;
    const int row = idx >> 1, half = idx & 1;
    const int R = n0 + row;
    if (R < NN) {
      bf16x8 v = *(const bf16x8*)(lsA + row * LSTR + g2 * 16 + half * 8);
      *(bf16x8*)(hout + (size_t)g2 * (NN * 16) + (size_t)R * 16 + half * 8) = v;
    }
  }
}

// ---------------------------------------------------------------------------
// K3: one 1024-thread block per bucket. segbase from LDS scan of bhist;
// per-dst histogram + scan -> off[]; scatter srcs into LDS csr segment;
// coalesced copy-out.
// ---------------------------------------------------------------------------
__global__ __launch_bounds__(1024) void bucket_to_csr(
    const int2* __restrict__ ebuf, const int* __restrict__ bhist,
    int* __restrict__ off, int* __restrict__ csr) {
  __shared__ int gs[NBUK];
  __shared__ int dh[512];
  __shared__ int s[512];
  __shared__ int lcur[512];
  __shared__ int lcsr[CAP];  // 40 KB
  const int b = blockIdx.x, t = threadIdx.x;

  if (t < NBUK) gs[t] = bhist[t];
  __syncthreads();
  for (int d = 1; d < NBUK; d <<= 1) {
    int a0 = 0;
    if (t < NBUK && t >= d) a0 = gs[t - d];
    __syncthreads();
    if (t < NBUK) gs[t] += a0;
    __syncthreads();
  }
  const int seglen = bhist[b];
  const int segbase = gs[b] - seglen;
  const int lo = b * DPB;
  const int hi = min(NN, lo + DPB);
  const int nd = hi - lo;
  const int2* eb = ebuf + segbase;

  if (t < 512) dh[t] = 0;
  __syncthreads();
  for (int i = t; i < seglen; i += 1024) atomicAdd(&dh[eb[i].y - lo], 1);
  __syncthreads();

  if (t < 512) s[t] = dh[t];
  __syncthreads();
  for (int d = 1; d < 512; d <<= 1) {
    int a0 = 0;
    if (t < 512 && t >= d) a0 = s[t - d];
    __syncthreads();
    if (t < 512) s[t] += a0;
    __syncthreads();
  }
  if (t < 512) lcur[t] = s[t] - dh[t];  // exclusive
  if (t < nd) off[lo + t] = segbase + (s[t] - dh[t]);
  if (b == NBUK - 1 && t == 0) off[NN] = NE;
  __syncthreads();

  if (seglen <= CAP) {
    for (int i = t; i < seglen; i += 1024) {
      const int2 e = eb[i];
      const int p = atomicAdd(&lcur[e.y - lo], 1);
      lcsr[p] = e.x;
    }
    __syncthreads();
    for (int i = t; i < seglen; i += 1024) csr[segbase + i] = lcsr[i];
  } else {
    for (int i = t; i < seglen; i += 1024) {
      const int2 e = eb[i];
      const int p = atomicAdd(&lcur[e.y - lo], 1);
      csr[segbase + p] = e.x;
    }
  }
}

// ---------------------------------------------------------------------------
// K4: LDS-csr gather. g = blockIdx&7 -> column group == XCD. Block covers
// GNB=256 consecutive nodes; their csr segment is contiguous (globally
// dst-sorted) -> staged once into LDS coalesced. Edge loop: ds_read csr +
// ONE uint2 h load per edge per lane (4 lanes/node, 8B each = 32B segment).
// Each 4-lane group owns 4 sequential nodes.
// ---------------------------------------------------------------------------
__global__ __launch_bounds__(256) void gather_bn_relu(
    const short* __restrict__ h, const int* __restrict__ off,
    const int* __restrict__ csr, const float* __restrict__ scsh,
    float* __restrict__ out) {
  __shared__ int loff[GNB + 1];
  __shared__ int lcsr[CAP2];  // 20 KB
  const int g = blockIdx.x & 7;
  const int nb0 = (blockIdx.x >> 3) * GNB;
  const int t = threadIdx.x;
  const int nnb = min(GNB, NN - nb0);

  for (int i = t; i <= nnb; i += 256) loff[i] = off[nb0 + i];
  __syncthreads();
  const int s0 = loff[0];
  const int seglen = loff[nnb] - s0;
  const int stg = min(seglen, CAP2);
  for (int i = t; i < stg; i += 256) lcsr[i] = csr[s0 + i];
  __syncthreads();

  const int c4 = t & 3;           // lane's 4 natural cols: g*16 + c4*4 ..+3
  const int lgid = t >> 2;        // 64 lane-groups, 4 nodes each
  const short* hg = h + (size_t)g * (NN * 16);
  const float4 sc = *(const float4*)(scsh + g * 16 + c4 * 4);
  const float4 sh = *(const float4*)(scsh + CC + g * 16 + c4 * 4);

  if (seglen <= CAP2) {
#pragma unroll
    for (int nn = 0; nn < 4; ++nn) {
      const int l = lgid * 4 + nn;
      if (l < nnb) {
        const int s = loff[l] - s0, e = loff[l + 1] - s0;
        float a0 = 0.f, a1 = 0.f, a2 = 0.f, a3 = 0.f;
        int i = s;
        for (; i + 4 <= e; i += 4) {
          const int e0 = lcsr[i], e1 = lcsr[i + 1];
          const int e2 = lcsr[i + 2], e3 = lcsr[i + 3];
          const uint2 p0 = *(const uint2*)(hg + (size_t)e0 * 16 + c4 * 4);
          const uint2 p1 = *(const uint2*)(hg + (size_t)e1 * 16 + c4 * 4);
          const uint2 p2 = *(const uint2*)(hg + (size_t)e2 * 16 + c4 * 4);
          const uint2 p3 = *(const uint2*)(hg + (size_t)e3 * 16 + c4 * 4);
          a0 += (bflo(p0.x) + bflo(p1.x)) + (bflo(p2.x) + bflo(p3.x));
          a1 += (bfhi(p0.x) + bfhi(p1.x)) + (bfhi(p2.x) + bfhi(p3.x));
          a2 += (bflo(p0.y) + bflo(p1.y)) + (bflo(p2.y) + bflo(p3.y));
          a3 += (bfhi(p0.y) + bfhi(p1.y)) + (bfhi(p2.y) + bfhi(p3.y));
        }
        for (; i < e; ++i) {
          const uint2 p = *(const uint2*)(hg + (size_t)lcsr[i] * 16 + c4 * 4);
          a0 += bflo(p.x); a1 += bfhi(p.x);
          a2 += bflo(p.y); a3 += bfhi(p.y);
        }
        const int node = nb0 + l;
        const float inv = (e > s) ? 1.0f / (float)(e - s) : 0.0f;
        float4 o;
        o.x = fmaxf(0.f, a0 * inv * sc.x + sh.x);
        o.y = fmaxf(0.f, a1 * inv * sc.y + sh.y);
        o.z = fmaxf(0.f, a2 * inv * sc.z + sh.z);
        o.w = fmaxf(0.f, a3 * inv * sc.w + sh.w);
        *(float4*)(out + (size_t)node * CC + g * 16 + c4 * 4) = o;
      }
    }
  } else {
    // astronomically rare (seglen > mean+16sigma): csr straight from global
    for (int nn = 0; nn < 4; ++nn) {
      const int l = lgid * 4 + nn;
      if (l < nnb) {
        const int s = loff[l], e = loff[l + 1];
        float a0 = 0.f, a1 = 0.f, a2 = 0.f, a3 = 0.f;
        for (int i = s; i < e; ++i) {
          const uint2 p = *(const uint2*)(hg + (size_t)csr[i] * 16 + c4 * 4);
          a0 += bflo(p.x); a1 += bfhi(p.x);
          a2 += bflo(p.y); a3 += bfhi(p.y);
        }
        const int node = nb0 + l;
        const float inv = (e > s) ? 1.0f / (float)(e - s) : 0.0f;
        float4 o;
        o.x = fmaxf(0.f, a0 * inv * sc.x + sh.x);
        o.y = fmaxf(0.f, a1 * inv * sc.y + sh.y);
        o.z = fmaxf(0.f, a2 * inv * sc.z + sh.z);
        o.w = fmaxf(0.f, a3 * inv * sc.w + sh.w);
        *(float4*)(out + (size_t)node * CC + g * 16 + c4 * 4) = o;
      }
    }
  }
}

// ---------------------------------------------------------------------------
// Fallback (small ws): atomic scatter + fp32 vector GEMM.
// ---------------------------------------------------------------------------
__global__ __launch_bounds__(256) void edge_scatter(
    const float* __restrict__ x, const int* __restrict__ ei,
    float* __restrict__ sums, int* __restrict__ cnt) {
  int gt = blockIdx.x * 256 + threadIdx.x;
  int e = gt >> 5;
  int sub = gt & 31;
  if (e >= NE) return;
  int src = ei[e];
  int dst = ei[NE + e];
  const float4 v = *(const float4*)(x + (size_t)src * CC + sub * 4);
  float* o = sums + (size_t)dst * CC + sub * 4;
  unsafeAtomicAdd(o + 0, v.x);
  unsafeAtomicAdd(o + 1, v.y);
  unsafeAtomicAdd(o + 2, v.z);
  unsafeAtomicAdd(o + 3, v.w);
  if (sub == 0) atomicAdd(cnt + dst, 1);
}

__global__ __launch_bounds__(256) void gemm_bn_relu_fb(
    float* buf, const float* __restrict__ W, const float* __restrict__ bias,
    const float* __restrict__ gamma, const float* __restrict__ beta,
    const float* __restrict__ rmean, const float* __restrict__ rvar,
    const int* __restrict__ cnt) {
  __shared__ float xsT[CC][65];
  const int t = threadIdx.x;
  const int n0 = blockIdx.x * 64;
  for (int j = 0; j < 8; ++j) {
    int i = t + 256 * j;
    int row = i >> 5;
    int ko = (i & 31) * 4;
    float4 v = make_float4(0.f, 0.f, 0.f, 0.f);
    if (n0 + row < NN) v = *(const float4*)(buf + (size_t)(n0 + row) * CC + ko);
    xsT[ko + 0][row] = v.x;
    xsT[ko + 1][row] = v.y;
    xsT[ko + 2][row] = v.z;
    xsT[ko + 3][row] = v.w;
  }
  __syncthreads();
  const int cg = t & 31;
  const int ng8 = (t >> 5) * 8;
  float acc[8][4];
#pragma unroll
  for (int j = 0; j < 8; ++j)
#pragma unroll
    for (int c = 0; c < 4; ++c) acc[j][c] = 0.f;
#pragma unroll 8
  for (int k = 0; k < CC; ++k) {
    const float4 wv = *(const float4*)(W + k * CC + cg * 4);
#pragma unroll
    for (int j = 0; j < 8; ++j) {
      const float xv = xsT[k][ng8 + j];
      acc[j][0] = fmaf(xv, wv.x, acc[j][0]);
      acc[j][1] = fmaf(xv, wv.y, acc[j][1]);
      acc[j][2] = fmaf(xv, wv.z, acc[j][2]);
      acc[j][3] = fmaf(xv, wv.w, acc[j][3]);
    }
  }
  const float4 bb = *(const float4*)(bias + cg * 4);
  const float4 gg = *(const float4*)(gamma + cg * 4);
  const float4 bt = *(const float4*)(beta + cg * 4);
  const float4 mu = *(const float4*)(rmean + cg * 4);
  const float4 vr = *(const float4*)(rvar + cg * 4);
  float sc[4], sh[4];
  sc[0] = gg.x * rsqrtf(vr.x + BN_EPS);
  sc[1] = gg.y * rsqrtf(vr.y + BN_EPS);
  sc[2] = gg.z * rsqrtf(vr.z + BN_EPS);
  sc[3] = gg.w * rsqrtf(vr.w + BN_EPS);
  sh[0] = bt.x - mu.x * sc[0];
  sh[1] = bt.y - mu.y * sc[1];
  sh[2] = bt.z - mu.z * sc[2];
  sh[3] = bt.w - mu.w * sc[3];
#pragma unroll
  for (int j = 0; j < 8; ++j) {
    const int n = n0 + ng8 + j;
    if (n >= NN) continue;
    const int cn = cnt[n];
    const float inv = cn > 0 ? 1.0f / (float)cn : 0.0f;
    const float bsel = cn > 0 ? 1.0f : 0.0f;
    float4 o;
    o.x = fmaxf(0.f, (acc[j][0] * inv + bsel * bb.x) * sc[0] + sh[0]);
    o.y = fmaxf(0.f, (acc[j][1] * inv + bsel * bb.y) * sc[1] + sh[1]);
    o.z = fmaxf(0.f, (acc[j][2] * inv + bsel * bb.z) * sc[2] + sh[2]);
    o.w = fmaxf(0.f, (acc[j][3] * inv + bsel * bb.w) * sc[3] + sh[3]);
    *(float4*)(buf + (size_t)n * CC + cg * 4) = o;
  }
}

extern "C" void kernel_launch(void* const* d_in, const int* in_sizes, int n_in,
                              void* d_out, int out_size, void* d_ws, size_t ws_size,
                              hipStream_t stream) {
  const float* x     = (const float*)d_in[0];
  const int*   ei    = (const int*)d_in[1];
  const float* W     = (const float*)d_in[2];
  const float* bias  = (const float*)d_in[3];
  const float* gamma = (const float*)d_in[4];
  const float* beta  = (const float*)d_in[5];
  const float* rmean = (const float*)d_in[6];
  const float* rvar  = (const float*)d_in[7];
  float* out = (float*)d_out;

  // ws layout (bytes):
  //   off[NN+1] | bhist[256] | gcurz[256] (contiguous -> one 2KB memset)
  //   | csr[NE] | scsh[384f] | Wsw[16384 bf16] | ebuf int2[NE] | h[NN*CC bf16]
  const size_t OFF_B  = 0;
  const size_t BH_B   = 400128;
  const size_t GC_B   = 401152;
  const size_t CSR_B  = 802304;
  const size_t SCSH_B = 7202304;
  const size_t WSW_B  = 7204352;
  const size_t EB_B   = 7237120;
  const size_t H1_B   = 20037120;                     // tier-1 h (after ebuf)
  const size_t NEED1  = H1_B + (size_t)NN * CC * 2;   // 45,637,120
  const size_t NEED2  = EB_B + (size_t)NN * CC * 2;   // 32,837,120 (alias)

  const int GGRID = ((NN + GNB - 1) / GNB) * 8;  // 391 node-blocks x 8 groups

  if (ws_size >= NEED2) {
    int*   off   = (int*)((char*)d_ws + OFF_B);
    int*   bhist = (int*)((char*)d_ws + BH_B);
    int*   gcurz = (int*)((char*)d_ws + GC_B);
    int*   csr   = (int*)((char*)d_ws + CSR_B);
    float* scsh  = (float*)((char*)d_ws + SCSH_B);
    short* Wsw   = (short*)((char*)d_ws + WSW_B);

    hipMemsetAsync(bhist, 0, 2048, stream);  // bhist + gcurz
    prep_hist<<<ABLK, 256, 0, stream>>>(W, bias, gamma, beta, rmean, rvar,
                                        ei, Wsw, scsh, bhist);
    if (ws_size >= NEED1) {
      // tier 1: fused scatter+linear (ebuf and h distinct)
      int2*  ebuf = (int2*)((char*)d_ws + EB_B);
      short* h    = (short*)((char*)d_ws + H1_B);
      scatter_linear<<<ABLK + LBLK, 256, 0, stream>>>(
          ei, bhist, gcurz, ebuf, x, Wsw, scsh, h, ABLK);
      bucket_to_csr<<<NBUK, 1024, 0, stream>>>(ebuf, bhist, off, csr);
      gather_bn_relu<<<GGRID, 256, 0, stream>>>(h, off, csr, scsh, out);
    } else {
      // tier 2: un-fused, ebuf aliases h (r8-proven ordering)
      int2*  ebuf = (int2*)((char*)d_ws + EB_B);
      short* h    = (short*)((char*)d_ws + EB_B);
      scatter_linear<<<ABLK, 256, 0, stream>>>(
          ei, bhist, gcurz, ebuf, x, Wsw, scsh, h, ABLK);  // scatter only
      bucket_to_csr<<<NBUK, 1024, 0, stream>>>(ebuf, bhist, off, csr);
      scatter_linear<<<LBLK, 256, 0, stream>>>(
          ei, bhist, gcurz, ebuf, x, Wsw, scsh, h, 0);     // linear only
      gather_bn_relu<<<GGRID, 256, 0, stream>>>(h, off, csr, scsh, out);
    }
  } else {
    int* cnt = (int*)d_ws;
    hipMemsetAsync(out, 0, (size_t)NN * CC * sizeof(float), stream);
    hipMemsetAsync(cnt, 0, (size_t)NN * sizeof(int), stream);
    edge_scatter<<<(NE * 32) / 256, 256, 0, stream>>>(x, ei, out, cnt);
    gemm_bn_relu_fb<<<(NN + 63) / 64, 256, 0, stream>>>(
        out, W, bias, gamma, beta, rmean, rvar, cnt);
  }
}